// Round 4
// baseline (648.868 us; speedup 1.0000x reference)
//
#include <hip/hip_runtime.h>
#include <cstdint>
#include <cstddef>

typedef __bf16 bf16x8 __attribute__((ext_vector_type(8)));
typedef float f32x4 __attribute__((ext_vector_type(4)));
typedef unsigned short u16x8 __attribute__((ext_vector_type(8)));

#define VT_LD 56  // padded j-stride of V^T rows
#define LDE 144   // epilogue LDS row stride (shorts)

__device__ __forceinline__ unsigned short f2bf(float f) {
  __bf16 h = (__bf16)f;                       // RNE via v_cvt_pk_bf16_f32 (m240)
  return __builtin_bit_cast(unsigned short, h);
}

__device__ __forceinline__ void gload_lds16(const void* g, void* l) {
  __builtin_amdgcn_global_load_lds((const __attribute__((address_space(1))) void*)g,
                                   (__attribute__((address_space(3))) void*)l, 16, 0, 0);
}

// ---------------- kernel 0: generic fp32 -> bf16 (vec8, grid-stride) ----------------
__global__ void conv_f2b_k(const float* __restrict__ src, unsigned short* __restrict__ dst, long n8) {
  long i = (long)blockIdx.x * blockDim.x + threadIdx.x;
  long stride = (long)gridDim.x * blockDim.x;
  for (; i < n8; i += stride) {
    float4 a = *(const float4*)(src + i * 8);
    float4 b = *(const float4*)(src + i * 8 + 4);
    u16x8 p;
    p[0]=f2bf(a.x); p[1]=f2bf(a.y); p[2]=f2bf(a.z); p[3]=f2bf(a.w);
    p[4]=f2bf(b.x); p[5]=f2bf(b.y); p[6]=f2bf(b.z); p[7]=f2bf(b.w);
    *(u16x8*)(dst + i * 8) = p;
  }
}

// ---------------- kernel 0b: bias table [16][49][49] fp32 ----------------
__global__ void build_bias_k(const float* __restrict__ rpb, float* __restrict__ biasT) {
  int idx = blockIdx.x * 256 + threadIdx.x;
  if (idx >= 16 * 2401) return;
  int h = idx / 2401;
  int rem = idx - h * 2401;
  int i = rem / 49, j = rem - (rem / 49) * 49;
  int r1 = i / 7, c1 = i - r1 * 7;
  int r2 = j / 7, c2 = j - r2 * 7;
  int ri = (r1 - r2 + 6) * 13 + (c1 - c2 + 6);
  biasT[idx] = rpb[ri * 16 + h];
}

// ---------------- kernel 1: QKV projection GEMM (BK=64, 2-plane LDS) ----------------
// out[m][n] = sum_k xb[m][k] * wb[n][k] + b[n]; M=100352, N=1536, K=512
// LDS per operand: [plane ks][128 rows][32 shorts], chunk-swizzled c^((row>>1)&3).
__global__ __launch_bounds__(256, 3) void qkv_gemm_k(
    const unsigned short* __restrict__ xb, const float* __restrict__ qkv_b,
    const unsigned short* __restrict__ wb,
    unsigned short* __restrict__ qs, unsigned short* __restrict__ kk,
    unsigned short* __restrict__ vt)
{
  // A: [0,8192) shorts, B: [8192,16384); epilogue aliases [0,18432)
  __shared__ __align__(16) unsigned short smem[18432];
  unsigned short* Ab = smem;
  unsigned short* Bb = smem + 8192;

  int bid = blockIdx.x;
  int sw = (bid & 7) * 1176 + (bid >> 3);   // 9408 % 8 == 0 -> bijective
  int mt = sw / 12, nt = sw - mt * 12;      // N fast: 12 blocks share one A panel
  long m0 = (long)mt * 128;
  int  n0 = nt * 128;
  int  s  = n0 >> 9;                        // block-uniform output kind

  int t = threadIdx.x;
  int lane = t & 63, wv = t >> 6;
  int g = lane >> 4, q = lane & 15;
  int wrow = wv >> 1, wcol = wv & 1;

  f32x4 acc[4][4] = {};

  // Staging: wave wv issues calls ci = wv*4+c; plane p = ci>>3, rowgroup rg = ci&7.
  // Lane l: row = rg*16 + (l>>2); inverse-swizzled global chunk cg = (l&3)^((l>>3)&3).
  int cg = (lane & 3) ^ ((lane >> 3) & 3);
  int lrow = lane >> 2;
  const unsigned short* agp[4];
  const unsigned short* bgp[4];
  unsigned short* alb[4];
  unsigned short* blb[4];
  #pragma unroll
  for (int c = 0; c < 4; ++c) {
    int ci = wv * 4 + c;
    int p = ci >> 3, rg = ci & 7;
    int row = rg * 16 + lrow;
    agp[c] = xb + (m0 + row) * 512 + p * 32 + cg * 8;
    bgp[c] = wb + (size_t)(n0 + row) * 512 + p * 32 + cg * 8;
    alb[c] = Ab + ci * 512;                 // wave-uniform LDS base (1024 B/call)
    blb[c] = Bb + ci * 512;
  }

  // Frag-read bases (per plane ks): row = {wrow|wcol}*64 + q, chunk g^((q>>1)&3)
  int csw = (g ^ ((q >> 1) & 3)) * 8;
  const unsigned short* ar0 = Ab + (wrow * 64 + q) * 32 + csw;
  const unsigned short* ar1 = ar0 + 4096;
  const unsigned short* br0 = Bb + (wcol * 64 + q) * 32 + csw;
  const unsigned short* br1 = br0 + 4096;

  #pragma unroll
  for (int kt = 0; kt < 8; ++kt) {
    int k0 = kt * 64;
    #pragma unroll
    for (int c = 0; c < 4; ++c) {
      gload_lds16(agp[c] + k0, alb[c]);
      gload_lds16(bgp[c] + k0, blb[c]);
    }
    __syncthreads();   // drains vmcnt (global_load_lds)

    bf16x8 af[4], bfr[4];
    #pragma unroll
    for (int i2 = 0; i2 < 4; ++i2) af[i2]  = *(const bf16x8*)(ar0 + i2 * 512);
    #pragma unroll
    for (int j2 = 0; j2 < 4; ++j2) bfr[j2] = *(const bf16x8*)(br0 + j2 * 512);
    #pragma unroll
    for (int i2 = 0; i2 < 4; ++i2)
      #pragma unroll
      for (int j2 = 0; j2 < 4; ++j2)
        acc[i2][j2] = __builtin_amdgcn_mfma_f32_16x16x32_bf16(af[i2], bfr[j2], acc[i2][j2], 0, 0, 0);
    #pragma unroll
    for (int i2 = 0; i2 < 4; ++i2) af[i2]  = *(const bf16x8*)(ar1 + i2 * 512);
    #pragma unroll
    for (int j2 = 0; j2 < 4; ++j2) bfr[j2] = *(const bf16x8*)(br1 + j2 * 512);
    #pragma unroll
    for (int i2 = 0; i2 < 4; ++i2)
      #pragma unroll
      for (int j2 = 0; j2 < 4; ++j2)
        acc[i2][j2] = __builtin_amdgcn_mfma_f32_16x16x32_bf16(af[i2], bfr[j2], acc[i2][j2], 0, 0, 0);
    __syncthreads();
  }

  // ---- epilogue ----
  int   nl[4];
  float bias[4];
  #pragma unroll
  for (int j2 = 0; j2 < 4; ++j2) {
    nl[j2] = wcol * 64 + j2 * 16 + q;
    bias[j2] = qkv_b[n0 + nl[j2]];
  }

  if (s < 2) {
    // Q/K: restage tile through LDS, vectorized 16B stores
    float sc = (s == 0) ? 0.17677669529663687f : 1.0f;
    #pragma unroll
    for (int i2 = 0; i2 < 4; ++i2) {
      #pragma unroll
      for (int r = 0; r < 4; ++r) {
        int ml = wrow * 64 + i2 * 16 + 4 * g + r;
        #pragma unroll
        for (int j2 = 0; j2 < 4; ++j2)
          smem[ml * LDE + nl[j2]] = f2bf((acc[i2][j2][r] + bias[j2]) * sc);
      }
    }
    __syncthreads();
    unsigned short* dst = (s == 0) ? qs : kk;
    int c8 = (t & 15) * 8;
    int d0 = c8 & 31;
    int h  = ((n0 + c8) >> 5) & 15;
    #pragma unroll
    for (int p = 0; p < 8; ++p) {
      int row = p * 16 + (t >> 4);
      unsigned int gm = (unsigned int)m0 + row;
      unsigned int b  = gm / 49;
      unsigned int i  = gm - b * 49;
      u16x8 val = *(const u16x8*)(smem + row * LDE + c8);
      *(u16x8*)(dst + ((size_t)(b * 16 + h) * 49 + i) * 32 + d0) = val;
    }
  } else {
    // V: thread's 4 r-values are consecutive i in VT -> packed dword stores
    #pragma unroll
    for (int j2 = 0; j2 < 4; ++j2) {
      int d = nl[j2] & 31;
      int h = ((n0 + nl[j2]) >> 5) & 15;
      #pragma unroll
      for (int i2 = 0; i2 < 4; ++i2) {
        unsigned int gm0 = (unsigned int)m0 + wrow * 64 + i2 * 16 + 4 * g;
        unsigned int b0 = gm0 / 49;
        unsigned int i0 = gm0 - b0 * 49;
        unsigned short hv[4];
        #pragma unroll
        for (int r = 0; r < 4; ++r) hv[r] = f2bf(acc[i2][j2][r] + bias[j2]);
        if (i0 <= 45) {
          unsigned short* base = vt + ((size_t)(b0 * 16 + h) * 32 + d) * VT_LD;
          if ((i0 & 1) == 0) {
            *(unsigned int*)(base + i0)     = (unsigned int)hv[0] | ((unsigned int)hv[1] << 16);
            *(unsigned int*)(base + i0 + 2) = (unsigned int)hv[2] | ((unsigned int)hv[3] << 16);
          } else {
            base[i0] = hv[0];
            *(unsigned int*)(base + i0 + 1) = (unsigned int)hv[1] | ((unsigned int)hv[2] << 16);
            base[i0 + 3] = hv[3];
          }
        } else {
          #pragma unroll
          for (int r = 0; r < 4; ++r) {
            unsigned int gm = gm0 + r;
            unsigned int b = gm / 49;
            unsigned int i = gm - b * 49;
            vt[((size_t)(b * 16 + h) * 32 + d) * VT_LD + i] = hv[r];
          }
        }
      }
    }
  }
}

// ---------------- kernel 2: fused window attention ----------------
__global__ __launch_bounds__(256, 3) void win_attn_k(
    const unsigned short* __restrict__ qs, const unsigned short* __restrict__ kk,
    const unsigned short* __restrict__ vt, const float* __restrict__ biasT,
    const float* __restrict__ mask, float* __restrict__ out)
{
  __shared__ float mlds[49 * 49];
  __shared__ unsigned short plds[4][64 * 72];   // per-wave P, +8 pad

  int b = blockIdx.x;
  int t = threadIdx.x;
  int lane = t & 63, wv = t >> 6;
  int g = lane >> 4, q = lane & 15;

  const float* msrc = mask + (size_t)(b & 63) * 2401;
  for (int idx = t; idx < 2401; idx += 256) mlds[idx] = msrc[idx];
  __syncthreads();

  unsigned short* pl = plds[wv];

  for (int hh = 0; hh < 4; ++hh) {
    int h = wv * 4 + hh;
    const unsigned short* qh = qs + (size_t)(b * 16 + h) * (49 * 32);
    const unsigned short* kh = kk + (size_t)(b * 16 + h) * (49 * 32);
    const unsigned short* vh = vt + (size_t)(b * 16 + h) * (32 * VT_LD);
    const float* bhp = biasT + h * 2401;

    // S = (Q*scale) @ K^T   [64x64 padded, valid 49x49]
    bf16x8 aq[4], bk[4];
    #pragma unroll
    for (int it = 0; it < 4; ++it) {
      int row = it * 16 + q; row = row > 48 ? 48 : row;   // clamp pad rows
      aq[it] = *(const bf16x8*)(qh + row * 32 + 8 * g);
    }
    #pragma unroll
    for (int jt = 0; jt < 4; ++jt) {
      int row = jt * 16 + q; row = row > 48 ? 48 : row;
      bk[jt] = *(const bf16x8*)(kh + row * 32 + 8 * g);
    }
    f32x4 zero = {0.f, 0.f, 0.f, 0.f};
    f32x4 st[4][4];
    __builtin_amdgcn_s_setprio(1);
    #pragma unroll
    for (int it = 0; it < 4; ++it)
      #pragma unroll
      for (int jt = 0; jt < 4; ++jt)
        st[it][jt] = __builtin_amdgcn_mfma_f32_16x16x32_bf16(aq[it], bk[jt], zero, 0, 0, 0);
    __builtin_amdgcn_s_setprio(0);

    // bias + mask + row softmax (rows: i = it*16 + 4g + r; cols j = jt*16 + q)
    float rinv[4][4];
    #pragma unroll
    for (int it = 0; it < 4; ++it) {
      #pragma unroll
      for (int r = 0; r < 4; ++r) {
        int i = it * 16 + 4 * g + r;
        int ic = i > 48 ? 48 : i;
        float vj[4];
        #pragma unroll
        for (int jt = 0; jt < 4; ++jt) {
          int j = jt * 16 + q;
          float val;
          if (j < 49) val = st[it][jt][r] + bhp[ic * 49 + j] + mlds[ic * 49 + j];
          else        val = -__builtin_inff();
          vj[jt] = val;
        }
        float mx = fmaxf(fmaxf(vj[0], vj[1]), fmaxf(vj[2], vj[3]));
        #pragma unroll
        for (int off = 1; off < 16; off <<= 1) mx = fmaxf(mx, __shfl_xor(mx, off));
        float sm = 0.f;
        #pragma unroll
        for (int jt = 0; jt < 4; ++jt) {
          float p = __expf(vj[jt] - mx);   // j>=49 -> exp(-inf)=0
          st[it][jt][r] = p;
          sm += p;
        }
        #pragma unroll
        for (int off = 1; off < 16; off <<= 1) sm += __shfl_xor(sm, off);
        rinv[it][r] = 1.0f / sm;           // sm >= 1
      }
    }

    // P -> LDS (bf16, unnormalized). Same-wave region: no barrier needed.
    #pragma unroll
    for (int it = 0; it < 4; ++it)
      #pragma unroll
      for (int jt = 0; jt < 4; ++jt)
        #pragma unroll
        for (int r = 0; r < 4; ++r) {
          int i = it * 16 + 4 * g + r;
          int j = jt * 16 + q;
          pl[i * 72 + j] = f2bf(st[it][jt][r]);
        }

    // O = P @ V  via VT (B frag: k=j contiguous along VT rows)
    f32x4 oacc[4][2] = {};
    #pragma unroll
    for (int ktt = 0; ktt < 2; ++ktt) {
      bf16x8 pa[4], bv[2];
      #pragma unroll
      for (int it = 0; it < 4; ++it)
        pa[it] = *(const bf16x8*)(pl + (it * 16 + q) * 72 + ktt * 32 + 8 * g);
      #pragma unroll
      for (int dt = 0; dt < 2; ++dt)
        bv[dt] = *(const bf16x8*)(vh + (dt * 16 + q) * VT_LD + ktt * 32 + 8 * g);
      __builtin_amdgcn_s_setprio(1);
      #pragma unroll
      for (int it = 0; it < 4; ++it)
        #pragma unroll
        for (int dt = 0; dt < 2; ++dt)
          oacc[it][dt] = __builtin_amdgcn_mfma_f32_16x16x32_bf16(pa[it], bv[dt], oacc[it][dt], 0, 0, 0);
      __builtin_amdgcn_s_setprio(0);
    }

    // store fp32 output [b*49+i][h*32+d]
    #pragma unroll
    for (int it = 0; it < 4; ++it) {
      #pragma unroll
      for (int dt = 0; dt < 2; ++dt) {
        #pragma unroll
        for (int r = 0; r < 4; ++r) {
          int i = it * 16 + 4 * g + r;
          if (i < 49) {
            int d = dt * 16 + q;
            out[(size_t)(b * 49 + i) * 512 + h * 32 + d] = oacc[it][dt][r] * rinv[it][r];
          }
        }
      }
    }
  }
}

// ---------------- launcher ----------------
extern "C" void kernel_launch(void* const* d_in, const int* in_sizes, int n_in,
                              void* d_out, int out_size, void* d_ws, size_t ws_size,
                              hipStream_t stream) {
  const float* x     = (const float*)d_in[0];
  const float* mask  = (const float*)d_in[1];
  const float* qkv_w = (const float*)d_in[2];
  const float* qkv_b = (const float*)d_in[3];
  const float* rpb   = (const float*)d_in[4];
  float* out = (float*)d_out;

  // workspace layout (bytes)
  const size_t QS_OFF   = 0;                         // 2048*16*49*32*2 = 102,760,448
  const size_t KK_OFF   = 102760448;
  const size_t VT_OFF   = 205520896;                 // 2048*16*32*56*2 = 117,440,512
  const size_t BIAS_OFF = 322961408;                 // 16*49*49*4     = 153,664
  const size_t WB_OFF   = 323115072;                 // 1536*512*2     = 1,572,864
  const size_t NEED     = 324687936;
  if (ws_size < NEED) return;

  char* ws = (char*)d_ws;
  unsigned short* qsb   = (unsigned short*)(ws + QS_OFF);
  unsigned short* kkb   = (unsigned short*)(ws + KK_OFF);
  unsigned short* vtb   = (unsigned short*)(ws + VT_OFF);
  float*          biasT = (float*)(ws + BIAS_OFF);
  unsigned short* wb    = (unsigned short*)(ws + WB_OFF);

  // xb (bf16 x, 103 MB) lives in d_out (205 MB fp32) — dead until win_attn
  // fully overwrites it. Deterministic: rewritten every call.
  unsigned short* xb = (unsigned short*)d_out;

  conv_f2b_k<<<2048, 256, 0, stream>>>(x, xb, 6422528);        // 100352*512/8
  conv_f2b_k<<<512, 256, 0, stream>>>(qkv_w, wb, 98304);       // 1536*512/8
  build_bias_k<<<151, 256, 0, stream>>>(rpb, biasT);
  qkv_gemm_k<<<9408, 256, 0, stream>>>(xb, qkv_b, wb, qsb, kkb, vtb);
  win_attn_k<<<2048, 256, 0, stream>>>(qsb, kkb, vtb, biasT, mask, out);
}

// Round 5
// 503.483 us; speedup vs baseline: 1.2888x; 1.2888x over previous
//
#include <hip/hip_runtime.h>
#include <cstdint>
#include <cstddef>

typedef __bf16 bf16x8 __attribute__((ext_vector_type(8)));
typedef float f32x4 __attribute__((ext_vector_type(4)));
typedef unsigned short u16x8 __attribute__((ext_vector_type(8)));

#define VT_LD 56  // padded j-stride of V^T rows
#define LDE 144   // epilogue LDS row stride (shorts)

__device__ __forceinline__ unsigned short f2bf(float f) {
  unsigned int u = __builtin_bit_cast(unsigned int, f);
  u += 0x7FFFu + ((u >> 16) & 1u);   // RNE
  return (unsigned short)(u >> 16);
}

__device__ __forceinline__ void gload_lds16(const void* g, void* l) {
  __builtin_amdgcn_global_load_lds((const __attribute__((address_space(1))) void*)g,
                                   (__attribute__((address_space(3))) void*)l, 16, 0, 0);
}

// ---------------- kernel 0: generic fp32 -> bf16 (vec8, grid-stride) ----------------
__global__ void conv_f2b_k(const float* __restrict__ src, unsigned short* __restrict__ dst, long n8) {
  long i = (long)blockIdx.x * blockDim.x + threadIdx.x;
  long stride = (long)gridDim.x * blockDim.x;
  for (; i < n8; i += stride) {
    float4 a = *(const float4*)(src + i * 8);
    float4 b = *(const float4*)(src + i * 8 + 4);
    u16x8 p;
    p[0]=f2bf(a.x); p[1]=f2bf(a.y); p[2]=f2bf(a.z); p[3]=f2bf(a.w);
    p[4]=f2bf(b.x); p[5]=f2bf(b.y); p[6]=f2bf(b.z); p[7]=f2bf(b.w);
    *(u16x8*)(dst + i * 8) = p;
  }
}

// ---------------- kernel 0b: bias table [16][49][49] fp32 ----------------
__global__ void build_bias_k(const float* __restrict__ rpb, float* __restrict__ biasT) {
  int idx = blockIdx.x * 256 + threadIdx.x;
  if (idx >= 16 * 2401) return;
  int h = idx / 2401;
  int rem = idx - h * 2401;
  int i = rem / 49, j = rem - (rem / 49) * 49;
  int r1 = i / 7, c1 = i - r1 * 7;
  int r2 = j / 7, c2 = j - r2 * 7;
  int ri = (r1 - r2 + 6) * 13 + (c1 - c2 + 6);
  biasT[idx] = rpb[ri * 16 + h];
}

// ---------------- kernel 1: QKV projection GEMM (BK=32, 2-phase double-buffer) ----------------
// out[m][n] = sum_k xb[m][k] * wb[n][k] + b[n]; M=100352, N=1536, K=512
// LDS: A dbuf [2][128][32], B dbuf [2][128][32], chunk-swizzled c^((row>>1)&3).
__global__ __launch_bounds__(256, 3) void qkv_gemm_k(
    const unsigned short* __restrict__ xb, const float* __restrict__ qkv_b,
    const unsigned short* __restrict__ wb,
    unsigned short* __restrict__ qs, unsigned short* __restrict__ kk,
    unsigned short* __restrict__ vt)
{
  // A: [0,8192) shorts (2 bufs), B: [8192,16384); epilogue aliases [0,18432)
  __shared__ __align__(16) unsigned short smem[18432];
  unsigned short* Ab = smem;
  unsigned short* Bb = smem + 8192;

  int bid = blockIdx.x;
  int sw = (bid & 7) * 1176 + (bid >> 3);   // 9408 % 8 == 0 -> bijective
  int mt = sw / 12, nt = sw - mt * 12;      // N fast: 12 blocks share one A panel
  long m0 = (long)mt * 128;
  int  n0 = nt * 128;
  int  s  = n0 >> 9;                        // block-uniform output kind

  int t = threadIdx.x;
  int lane = t & 63, wv = t >> 6;
  int g = lane >> 4, q = lane & 15;
  int wrow = wv >> 1, wcol = wv & 1;

  f32x4 acc[4][4] = {};

  // Staging (rule #21): linear LDS dest (t*16B per section), inverse-swizzled
  // global source chunk schunk = (t&3) ^ ((row>>1)&3), row = t>>2.
  int schunk = (t & 3) ^ ((t >> 3) & 3);
  const unsigned short* ag0 = xb + (m0 + (t >> 2)) * 512 + schunk * 8;
  const unsigned short* ag1 = ag0 + 64 * 512;
  const unsigned short* bg0 = wb + (size_t)(n0 + (t >> 2)) * 512 + schunk * 8;
  const unsigned short* bg1 = bg0 + 64 * 512;
  unsigned short* alA  = Ab + wv * 512;           // wave-uniform LDS bases (buf0)
  unsigned short* alA2 = Ab + 2048 + wv * 512;
  unsigned short* blB  = Bb + wv * 512;
  unsigned short* blB2 = Bb + 2048 + wv * 512;

  // Swizzled frag-read base: rows == q (mod 16), chunk g ^ ((q>>1)&3)
  int roff = (8 * g) ^ (((q >> 1) & 3) << 3);
  const unsigned short* arb = Ab + (wrow * 64 + q) * 32 + roff;
  const unsigned short* brb = Bb + (wcol * 64 + q) * 32 + roff;

#define STAGE(KT, BOFF) do {                    \
    int kof = (KT) * 32;                        \
    gload_lds16(ag0 + kof, alA  + (BOFF));      \
    gload_lds16(ag1 + kof, alA2 + (BOFF));      \
    gload_lds16(bg0 + kof, blB  + (BOFF));      \
    gload_lds16(bg1 + kof, blB2 + (BOFF));      \
  } while (0)

#define COMPUTE(BOFF) do {                                                     \
    bf16x8 af[4], bfr[4];                                                      \
    _Pragma("unroll")                                                          \
    for (int i2 = 0; i2 < 4; ++i2) af[i2]  = *(const bf16x8*)(arb + (BOFF) + i2 * 512); \
    _Pragma("unroll")                                                          \
    for (int j2 = 0; j2 < 4; ++j2) bfr[j2] = *(const bf16x8*)(brb + (BOFF) + j2 * 512); \
    _Pragma("unroll")                                                          \
    for (int i2 = 0; i2 < 4; ++i2)                                             \
      _Pragma("unroll")                                                        \
      for (int j2 = 0; j2 < 4; ++j2)                                           \
        acc[i2][j2] = __builtin_amdgcn_mfma_f32_16x16x32_bf16(af[i2], bfr[j2], acc[i2][j2], 0, 0, 0); \
  } while (0)

  // 2-phase pipeline: loads for tile t+1 fly during compute of tile t.
  STAGE(0, 0);
  __syncthreads();
  for (int kt = 0; kt < 16; kt += 2) {
    STAGE(kt + 1, 4096);          // kt+1 <= 15 always
    COMPUTE(0);
    __syncthreads();              // drains vmcnt: tile kt+1 resident
    if (kt + 2 < 16) STAGE(kt + 2, 0);
    COMPUTE(4096);
    __syncthreads();
  }
#undef STAGE
#undef COMPUTE

  // ---- epilogue ----
  int   nl[4];
  float bias[4];
  #pragma unroll
  for (int j2 = 0; j2 < 4; ++j2) {
    nl[j2] = wcol * 64 + j2 * 16 + q;
    bias[j2] = qkv_b[n0 + nl[j2]];
  }

  if (s < 2) {
    // Q/K: restage tile through LDS, vectorized 16B stores
    float sc = (s == 0) ? 0.17677669529663687f : 1.0f;
    #pragma unroll
    for (int i2 = 0; i2 < 4; ++i2) {
      #pragma unroll
      for (int r = 0; r < 4; ++r) {
        int ml = wrow * 64 + i2 * 16 + 4 * g + r;
        #pragma unroll
        for (int j2 = 0; j2 < 4; ++j2)
          smem[ml * LDE + nl[j2]] = f2bf((acc[i2][j2][r] + bias[j2]) * sc);
      }
    }
    __syncthreads();
    unsigned short* dst = (s == 0) ? qs : kk;
    int c8 = (t & 15) * 8;
    int d0 = c8 & 31;
    int h  = ((n0 + c8) >> 5) & 15;
    #pragma unroll
    for (int p = 0; p < 8; ++p) {
      int row = p * 16 + (t >> 4);
      unsigned int gm = (unsigned int)m0 + row;
      unsigned int b  = gm / 49;
      unsigned int i  = gm - b * 49;
      u16x8 val = *(const u16x8*)(smem + row * LDE + c8);
      *(u16x8*)(dst + ((size_t)(b * 16 + h) * 49 + i) * 32 + d0) = val;
    }
  } else {
    // V: thread's 4 r-values are consecutive i in VT -> packed dword stores
    #pragma unroll
    for (int j2 = 0; j2 < 4; ++j2) {
      int d = nl[j2] & 31;
      int h = ((n0 + nl[j2]) >> 5) & 15;
      #pragma unroll
      for (int i2 = 0; i2 < 4; ++i2) {
        unsigned int gm0 = (unsigned int)m0 + wrow * 64 + i2 * 16 + 4 * g;
        unsigned int b0 = gm0 / 49;
        unsigned int i0 = gm0 - b0 * 49;
        unsigned short hv[4];
        #pragma unroll
        for (int r = 0; r < 4; ++r) hv[r] = f2bf(acc[i2][j2][r] + bias[j2]);
        if (i0 <= 45) {
          unsigned short* base = vt + ((size_t)(b0 * 16 + h) * 32 + d) * VT_LD;
          if ((i0 & 1) == 0) {
            *(unsigned int*)(base + i0)     = (unsigned int)hv[0] | ((unsigned int)hv[1] << 16);
            *(unsigned int*)(base + i0 + 2) = (unsigned int)hv[2] | ((unsigned int)hv[3] << 16);
          } else {
            base[i0] = hv[0];
            *(unsigned int*)(base + i0 + 1) = (unsigned int)hv[1] | ((unsigned int)hv[2] << 16);
            base[i0 + 3] = hv[3];
          }
        } else {
          #pragma unroll
          for (int r = 0; r < 4; ++r) {
            unsigned int gm = gm0 + r;
            unsigned int b = gm / 49;
            unsigned int i = gm - b * 49;
            vt[((size_t)(b * 16 + h) * 32 + d) * VT_LD + i] = hv[r];
          }
        }
      }
    }
  }
}

// ---------------- kernel 2: fused window attention (R3-proven config) ----------------
__global__ __launch_bounds__(256, 2) void win_attn_k(
    const unsigned short* __restrict__ qs, const unsigned short* __restrict__ kk,
    const unsigned short* __restrict__ vt, const float* __restrict__ biasT,
    const float* __restrict__ mask, float* __restrict__ out)
{
  __shared__ float mlds[49 * 49];
  __shared__ unsigned short plds[4][64 * 72];   // per-wave P, +8 pad

  int b = blockIdx.x;
  int t = threadIdx.x;
  int lane = t & 63, wv = t >> 6;
  int g = lane >> 4, q = lane & 15;

  const float* msrc = mask + (size_t)(b & 63) * 2401;
  for (int idx = t; idx < 2401; idx += 256) mlds[idx] = msrc[idx];
  __syncthreads();

  unsigned short* pl = plds[wv];

  for (int hh = 0; hh < 4; ++hh) {
    int h = wv * 4 + hh;
    const unsigned short* qh = qs + (size_t)(b * 16 + h) * (49 * 32);
    const unsigned short* kh = kk + (size_t)(b * 16 + h) * (49 * 32);
    const unsigned short* vh = vt + (size_t)(b * 16 + h) * (32 * VT_LD);
    const float* bhp = biasT + h * 2401;

    // S = (Q*scale) @ K^T   [64x64 padded, valid 49x49]
    bf16x8 aq[4], bk[4];
    #pragma unroll
    for (int it = 0; it < 4; ++it) {
      int row = it * 16 + q; row = row > 48 ? 48 : row;   // clamp pad rows
      aq[it] = *(const bf16x8*)(qh + row * 32 + 8 * g);
    }
    #pragma unroll
    for (int jt = 0; jt < 4; ++jt) {
      int row = jt * 16 + q; row = row > 48 ? 48 : row;
      bk[jt] = *(const bf16x8*)(kh + row * 32 + 8 * g);
    }
    f32x4 zero = {0.f, 0.f, 0.f, 0.f};
    f32x4 st[4][4];
    __builtin_amdgcn_s_setprio(1);
    #pragma unroll
    for (int it = 0; it < 4; ++it)
      #pragma unroll
      for (int jt = 0; jt < 4; ++jt)
        st[it][jt] = __builtin_amdgcn_mfma_f32_16x16x32_bf16(aq[it], bk[jt], zero, 0, 0, 0);
    __builtin_amdgcn_s_setprio(0);

    // bias + mask + row softmax (rows: i = it*16 + 4g + r; cols j = jt*16 + q)
    float rinv[4][4];
    #pragma unroll
    for (int it = 0; it < 4; ++it) {
      #pragma unroll
      for (int r = 0; r < 4; ++r) {
        int i = it * 16 + 4 * g + r;
        int ic = i > 48 ? 48 : i;
        float vj[4];
        #pragma unroll
        for (int jt = 0; jt < 4; ++jt) {
          int j = jt * 16 + q;
          float val;
          if (j < 49) val = st[it][jt][r] + bhp[ic * 49 + j] + mlds[ic * 49 + j];
          else        val = -__builtin_inff();
          vj[jt] = val;
        }
        float mx = fmaxf(fmaxf(vj[0], vj[1]), fmaxf(vj[2], vj[3]));
        #pragma unroll
        for (int off = 1; off < 16; off <<= 1) mx = fmaxf(mx, __shfl_xor(mx, off));
        float sm = 0.f;
        #pragma unroll
        for (int jt = 0; jt < 4; ++jt) {
          float p = __expf(vj[jt] - mx);   // j>=49 -> exp(-inf)=0
          st[it][jt][r] = p;
          sm += p;
        }
        #pragma unroll
        for (int off = 1; off < 16; off <<= 1) sm += __shfl_xor(sm, off);
        rinv[it][r] = 1.0f / sm;           // sm >= 1
      }
    }

    // P -> LDS (bf16, unnormalized). Same-wave region: no barrier needed.
    #pragma unroll
    for (int it = 0; it < 4; ++it)
      #pragma unroll
      for (int jt = 0; jt < 4; ++jt)
        #pragma unroll
        for (int r = 0; r < 4; ++r) {
          int i = it * 16 + 4 * g + r;
          int j = jt * 16 + q;
          pl[i * 72 + j] = f2bf(st[it][jt][r]);
        }

    // O = P @ V  via VT (B frag: k=j contiguous along VT rows)
    f32x4 oacc[4][2] = {};
    #pragma unroll
    for (int ktt = 0; ktt < 2; ++ktt) {
      bf16x8 pa[4], bv[2];
      #pragma unroll
      for (int it = 0; it < 4; ++it)
        pa[it] = *(const bf16x8*)(pl + (it * 16 + q) * 72 + ktt * 32 + 8 * g);
      #pragma unroll
      for (int dt = 0; dt < 2; ++dt)
        bv[dt] = *(const bf16x8*)(vh + (dt * 16 + q) * VT_LD + ktt * 32 + 8 * g);
      __builtin_amdgcn_s_setprio(1);
      #pragma unroll
      for (int it = 0; it < 4; ++it)
        #pragma unroll
        for (int dt = 0; dt < 2; ++dt)
          oacc[it][dt] = __builtin_amdgcn_mfma_f32_16x16x32_bf16(pa[it], bv[dt], oacc[it][dt], 0, 0, 0);
      __builtin_amdgcn_s_setprio(0);
    }

    // store fp32 output [b*49+i][h*32+d]
    #pragma unroll
    for (int it = 0; it < 4; ++it) {
      #pragma unroll
      for (int dt = 0; dt < 2; ++dt) {
        #pragma unroll
        for (int r = 0; r < 4; ++r) {
          int i = it * 16 + 4 * g + r;
          if (i < 49) {
            int d = dt * 16 + q;
            out[(size_t)(b * 49 + i) * 512 + h * 32 + d] = oacc[it][dt][r] * rinv[it][r];
          }
        }
      }
    }
  }
}

// ---------------- launcher ----------------
extern "C" void kernel_launch(void* const* d_in, const int* in_sizes, int n_in,
                              void* d_out, int out_size, void* d_ws, size_t ws_size,
                              hipStream_t stream) {
  const float* x     = (const float*)d_in[0];
  const float* mask  = (const float*)d_in[1];
  const float* qkv_w = (const float*)d_in[2];
  const float* qkv_b = (const float*)d_in[3];
  const float* rpb   = (const float*)d_in[4];
  float* out = (float*)d_out;

  // workspace layout (bytes)
  const size_t QS_OFF   = 0;                         // 2048*16*49*32*2 = 102,760,448
  const size_t KK_OFF   = 102760448;
  const size_t VT_OFF   = 205520896;                 // 2048*16*32*56*2 = 117,440,512
  const size_t BIAS_OFF = 322961408;                 // 16*49*49*4     = 153,664
  const size_t WB_OFF   = 323115072;                 // 1536*512*2     = 1,572,864
  const size_t NEED     = 324687936;
  if (ws_size < NEED) return;

  char* ws = (char*)d_ws;
  unsigned short* qsb   = (unsigned short*)(ws + QS_OFF);
  unsigned short* kkb   = (unsigned short*)(ws + KK_OFF);
  unsigned short* vtb   = (unsigned short*)(ws + VT_OFF);
  float*          biasT = (float*)(ws + BIAS_OFF);
  unsigned short* wb    = (unsigned short*)(ws + WB_OFF);

  // xb (bf16 x, 103 MB) lives in d_out (205 MB fp32) — dead until win_attn
  // fully overwrites it. Deterministic: rewritten every call.
  unsigned short* xb = (unsigned short*)d_out;

  conv_f2b_k<<<2048, 256, 0, stream>>>(x, xb, 6422528);        // 100352*512/8
  conv_f2b_k<<<512, 256, 0, stream>>>(qkv_w, wb, 98304);       // 1536*512/8
  build_bias_k<<<151, 256, 0, stream>>>(rpb, biasT);
  qkv_gemm_k<<<9408, 256, 0, stream>>>(xb, qkv_b, wb, qsb, kkb, vtb);
  win_attn_k<<<2048, 256, 0, stream>>>(qsb, kkb, vtb, biasT, mask, out);
}

// Round 6
// 441.838 us; speedup vs baseline: 1.4686x; 1.1395x over previous
//
#include <hip/hip_runtime.h>
#include <cstdint>
#include <cstddef>

typedef __bf16 bf16x8 __attribute__((ext_vector_type(8)));
typedef float f32x4 __attribute__((ext_vector_type(4)));
typedef unsigned short u16x8 __attribute__((ext_vector_type(8)));
typedef unsigned short u16x4 __attribute__((ext_vector_type(4)));
typedef unsigned int u32x2 __attribute__((ext_vector_type(2)));

#define VT_LD 56   // padded j-stride of V^T rows
#define LDE 144    // gemm epilogue LDS row stride (shorts)
#define BSTRIDE 52 // bias/mask row stride (elements)
#define BSZ 2548   // 49*52 per head
#define PLD 80     // P LDS row stride (shorts)

__device__ __forceinline__ unsigned short f2bf(float f) {
  unsigned int u = __builtin_bit_cast(unsigned int, f);
  u += 0x7FFFu + ((u >> 16) & 1u);   // RNE
  return (unsigned short)(u >> 16);
}
__device__ __forceinline__ float bf2f(unsigned short h) {
  unsigned int u = (unsigned int)h << 16;
  return __builtin_bit_cast(float, u);
}

__device__ __forceinline__ void gload_lds16(const void* g, void* l) {
  __builtin_amdgcn_global_load_lds((const __attribute__((address_space(1))) void*)g,
                                   (__attribute__((address_space(3))) void*)l, 16, 0, 0);
}

// ---------------- kernel 0: generic fp32 -> bf16 (vec8, grid-stride) ----------------
__global__ void conv_f2b_k(const float* __restrict__ src, unsigned short* __restrict__ dst, long n8) {
  long i = (long)blockIdx.x * blockDim.x + threadIdx.x;
  long stride = (long)gridDim.x * blockDim.x;
  for (; i < n8; i += stride) {
    float4 a = *(const float4*)(src + i * 8);
    float4 b = *(const float4*)(src + i * 8 + 4);
    u16x8 p;
    p[0]=f2bf(a.x); p[1]=f2bf(a.y); p[2]=f2bf(a.z); p[3]=f2bf(a.w);
    p[4]=f2bf(b.x); p[5]=f2bf(b.y); p[6]=f2bf(b.z); p[7]=f2bf(b.w);
    *(u16x8*)(dst + i * 8) = p;
  }
}

// ---------------- kernel 0b: bias table bf16 [16][49][52] (pad cols 49..51 = 0) ----------------
__global__ void build_bias_k(const float* __restrict__ rpb, unsigned short* __restrict__ biasT) {
  int idx = blockIdx.x * 256 + threadIdx.x;
  if (idx >= 16 * BSZ) return;
  int h = idx / BSZ;
  int rem = idx - h * BSZ;
  int i = rem / BSTRIDE, j = rem - (rem / BSTRIDE) * BSTRIDE;
  unsigned short v = 0;
  if (j < 49) {
    int r1 = i / 7, c1 = i - r1 * 7;
    int r2 = j / 7, c2 = j - r2 * 7;
    int ri = (r1 - r2 + 6) * 13 + (c1 - c2 + 6);
    v = f2bf(rpb[ri * 16 + h]);
  }
  biasT[idx] = v;
}

// ---------------- kernel 1: QKV projection GEMM (BK=32, 2-phase double-buffer) ----------------
__global__ __launch_bounds__(256, 3) void qkv_gemm_k(
    const unsigned short* __restrict__ xb, const float* __restrict__ qkv_b,
    const unsigned short* __restrict__ wb,
    unsigned short* __restrict__ qs, unsigned short* __restrict__ kk,
    unsigned short* __restrict__ vt)
{
  __shared__ __align__(16) unsigned short smem[18432];
  unsigned short* Ab = smem;
  unsigned short* Bb = smem + 8192;

  int bid = blockIdx.x;
  int sw = (bid & 7) * 1176 + (bid >> 3);   // 9408 % 8 == 0 -> bijective
  int mt = sw / 12, nt = sw - mt * 12;
  long m0 = (long)mt * 128;
  int  n0 = nt * 128;
  int  s  = n0 >> 9;

  int t = threadIdx.x;
  int lane = t & 63, wv = t >> 6;
  int g = lane >> 4, q = lane & 15;
  int wrow = wv >> 1, wcol = wv & 1;

  f32x4 acc[4][4] = {};

  int schunk = (t & 3) ^ ((t >> 3) & 3);
  const unsigned short* ag0 = xb + (m0 + (t >> 2)) * 512 + schunk * 8;
  const unsigned short* ag1 = ag0 + 64 * 512;
  const unsigned short* bg0 = wb + (size_t)(n0 + (t >> 2)) * 512 + schunk * 8;
  const unsigned short* bg1 = bg0 + 64 * 512;
  unsigned short* alA  = Ab + wv * 512;
  unsigned short* alA2 = Ab + 2048 + wv * 512;
  unsigned short* blB  = Bb + wv * 512;
  unsigned short* blB2 = Bb + 2048 + wv * 512;

  int roff = (8 * g) ^ (((q >> 1) & 3) << 3);
  const unsigned short* arb = Ab + (wrow * 64 + q) * 32 + roff;
  const unsigned short* brb = Bb + (wcol * 64 + q) * 32 + roff;

#define STAGE(KT, BOFF) do {                    \
    int kof = (KT) * 32;                        \
    gload_lds16(ag0 + kof, alA  + (BOFF));      \
    gload_lds16(ag1 + kof, alA2 + (BOFF));      \
    gload_lds16(bg0 + kof, blB  + (BOFF));      \
    gload_lds16(bg1 + kof, blB2 + (BOFF));      \
  } while (0)

#define COMPUTE(BOFF) do {                                                     \
    bf16x8 af[4], bfr[4];                                                      \
    _Pragma("unroll")                                                          \
    for (int i2 = 0; i2 < 4; ++i2) af[i2]  = *(const bf16x8*)(arb + (BOFF) + i2 * 512); \
    _Pragma("unroll")                                                          \
    for (int j2 = 0; j2 < 4; ++j2) bfr[j2] = *(const bf16x8*)(brb + (BOFF) + j2 * 512); \
    _Pragma("unroll")                                                          \
    for (int i2 = 0; i2 < 4; ++i2)                                             \
      _Pragma("unroll")                                                        \
      for (int j2 = 0; j2 < 4; ++j2)                                           \
        acc[i2][j2] = __builtin_amdgcn_mfma_f32_16x16x32_bf16(af[i2], bfr[j2], acc[i2][j2], 0, 0, 0); \
  } while (0)

  STAGE(0, 0);
  __syncthreads();
  for (int kt = 0; kt < 16; kt += 2) {
    STAGE(kt + 1, 4096);
    COMPUTE(0);
    __syncthreads();
    if (kt + 2 < 16) STAGE(kt + 2, 0);
    COMPUTE(4096);
    __syncthreads();
  }
#undef STAGE
#undef COMPUTE

  int   nl[4];
  float bias[4];
  #pragma unroll
  for (int j2 = 0; j2 < 4; ++j2) {
    nl[j2] = wcol * 64 + j2 * 16 + q;
    bias[j2] = qkv_b[n0 + nl[j2]];
  }

  if (s < 2) {
    float sc = (s == 0) ? 0.17677669529663687f : 1.0f;
    #pragma unroll
    for (int i2 = 0; i2 < 4; ++i2) {
      #pragma unroll
      for (int r = 0; r < 4; ++r) {
        int ml = wrow * 64 + i2 * 16 + 4 * g + r;
        #pragma unroll
        for (int j2 = 0; j2 < 4; ++j2)
          smem[ml * LDE + nl[j2]] = f2bf((acc[i2][j2][r] + bias[j2]) * sc);
      }
    }
    __syncthreads();
    unsigned short* dst = (s == 0) ? qs : kk;
    int c8 = (t & 15) * 8;
    int d0 = c8 & 31;
    int h  = ((n0 + c8) >> 5) & 15;
    #pragma unroll
    for (int p = 0; p < 8; ++p) {
      int row = p * 16 + (t >> 4);
      unsigned int gm = (unsigned int)m0 + row;
      unsigned int b  = gm / 49;
      unsigned int i  = gm - b * 49;
      u16x8 val = *(const u16x8*)(smem + row * LDE + c8);
      *(u16x8*)(dst + ((size_t)(b * 16 + h) * 49 + i) * 32 + d0) = val;
    }
  } else {
    #pragma unroll
    for (int j2 = 0; j2 < 4; ++j2) {
      int d = nl[j2] & 31;
      int h = ((n0 + nl[j2]) >> 5) & 15;
      #pragma unroll
      for (int i2 = 0; i2 < 4; ++i2) {
        unsigned int gm0 = (unsigned int)m0 + wrow * 64 + i2 * 16 + 4 * g;
        unsigned int b0 = gm0 / 49;
        unsigned int i0 = gm0 - b0 * 49;
        unsigned short hv[4];
        #pragma unroll
        for (int r = 0; r < 4; ++r) hv[r] = f2bf(acc[i2][j2][r] + bias[j2]);
        if (i0 <= 45) {
          unsigned short* base = vt + ((size_t)(b0 * 16 + h) * 32 + d) * VT_LD;
          if ((i0 & 1) == 0) {
            *(unsigned int*)(base + i0)     = (unsigned int)hv[0] | ((unsigned int)hv[1] << 16);
            *(unsigned int*)(base + i0 + 2) = (unsigned int)hv[2] | ((unsigned int)hv[3] << 16);
          } else {
            base[i0] = hv[0];
            *(unsigned int*)(base + i0 + 1) = (unsigned int)hv[1] | ((unsigned int)hv[2] << 16);
            base[i0 + 3] = hv[3];
          }
        } else {
          #pragma unroll
          for (int r = 0; r < 4; ++r) {
            unsigned int gm = gm0 + r;
            unsigned int b = gm / 49;
            unsigned int i = gm - b * 49;
            vt[((size_t)(b * 16 + h) * 32 + d) * VT_LD + i] = hv[r];
          }
        }
      }
    }
  }
}

// ---------------- kernel 2: fused window attention (swapped QK^T, lane-local rows) ----------------
__global__ __launch_bounds__(256, 2) void win_attn_k(
    const unsigned short* __restrict__ qs, const unsigned short* __restrict__ kk,
    const unsigned short* __restrict__ vt, const unsigned short* __restrict__ biasT,
    const float* __restrict__ mask, float* __restrict__ out)
{
  __shared__ float mlds[BSZ];                    // mask, stride-52 rows, pad cols = 0
  __shared__ unsigned short plds[4][64 * PLD];   // per-wave P

  int b = blockIdx.x;
  int t = threadIdx.x;
  int lane = t & 63, wv = t >> 6;
  int g = lane >> 4, q = lane & 15;

  const float* msrc = mask + (size_t)(b & 63) * 2401;
  for (int idx = t; idx < BSZ; idx += 256) {
    int i = idx / BSTRIDE, j = idx - (idx / BSTRIDE) * BSTRIDE;
    mlds[idx] = (j < 49) ? msrc[i * 49 + j] : 0.0f;
  }
  __syncthreads();

  unsigned short* pl = plds[wv];
  const float NINF = -__builtin_inff();

  // row indices (clamped) for frag loads: rows it*16+q, clamp>48 -> 48
  int rc[4];
  rc[0] = q; rc[1] = 16 + q; rc[2] = 32 + q; rc[3] = 48;

  // prologue: K/Q frags for first head
  int h0 = wv * 4;
  const unsigned short* qh = qs + (size_t)(b * 16 + h0) * (49 * 32);
  const unsigned short* kh = kk + (size_t)(b * 16 + h0) * (49 * 32);
  bf16x8 ak[4], bq[4];
  #pragma unroll
  for (int jt = 0; jt < 4; ++jt) ak[jt] = *(const bf16x8*)(kh + rc[jt] * 32 + 8 * g);
  #pragma unroll
  for (int it = 0; it < 4; ++it) bq[it] = *(const bf16x8*)(qh + rc[it] * 32 + 8 * g);

  #pragma unroll
  for (int hh = 0; hh < 4; ++hh) {
    int h = wv * 4 + hh;
    const unsigned short* vh  = vt + (size_t)(b * 16 + h) * (32 * VT_LD);
    const unsigned short* bh2 = biasT + h * BSZ;

    // S^T-swapped: st[it][jt] holds S[i=it*16+q][j=jt*16+4g+r]
    f32x4 zero = {0.f, 0.f, 0.f, 0.f};
    f32x4 st[4][4];
    __builtin_amdgcn_s_setprio(1);
    #pragma unroll
    for (int it = 0; it < 4; ++it)
      #pragma unroll
      for (int jt = 0; jt < 4; ++jt)
        st[it][jt] = __builtin_amdgcn_mfma_f32_16x16x32_bf16(ak[jt], bq[it], zero, 0, 0, 0);
    __builtin_amdgcn_s_setprio(0);

    // prefetch next head's frags (hides HBM latency under softmax)
    bf16x8 akn[4], bqn[4];
    if (hh < 3) {
      const unsigned short* qh2 = qh + 49 * 32;
      const unsigned short* kh2 = kh + 49 * 32;
      #pragma unroll
      for (int jt = 0; jt < 4; ++jt) akn[jt] = *(const bf16x8*)(kh2 + rc[jt] * 32 + 8 * g);
      #pragma unroll
      for (int it = 0; it < 4; ++it) bqn[it] = *(const bf16x8*)(qh2 + rc[it] * 32 + 8 * g);
      qh = qh2; kh = kh2;
    }
    // prefetch V frags for current head
    bf16x8 bv[2][2];
    #pragma unroll
    for (int ktt = 0; ktt < 2; ++ktt)
      #pragma unroll
      for (int dt = 0; dt < 2; ++dt)
        bv[ktt][dt] = *(const bf16x8*)(vh + (dt * 16 + q) * VT_LD + ktt * 32 + 8 * g);

    // softmax: rows are lane-local (i = it*16+q), j = jt*16+4g+r
    #pragma unroll
    for (int it = 0; it < 4; ++it) {
      int i = it * 16 + q;
      int ic = i > 48 ? 48 : i;
      f32x4 pv4[4];
      f32x4 vm = {NINF, NINF, NINF, NINF};
      #pragma unroll
      for (int jt = 0; jt < 4; ++jt) {
        if (jt == 3 && g > 0) {
          pv4[3] = (f32x4){NINF, NINF, NINF, NINF};
        } else {
          u16x4 bu = *(const u16x4*)(bh2 + ic * BSTRIDE + jt * 16 + 4 * g);
          f32x4 m4 = *(const f32x4*)(mlds + ic * BSTRIDE + jt * 16 + 4 * g);
          f32x4 sv = st[it][jt];
          #pragma unroll
          for (int r = 0; r < 4; ++r) sv[r] += bf2f(bu[r]) + m4[r];
          if (jt == 3) {            // g==0 here: j = 48+r, valid only r==0
            sv[1] = NINF; sv[2] = NINF; sv[3] = NINF;
          }
          pv4[jt] = sv;
          #pragma unroll
          for (int r = 0; r < 4; ++r) vm[r] = fmaxf(vm[r], sv[r]);
        }
      }
      float mx = fmaxf(fmaxf(vm[0], vm[1]), fmaxf(vm[2], vm[3]));
      mx = fmaxf(mx, __shfl_xor(mx, 16));
      mx = fmaxf(mx, __shfl_xor(mx, 32));
      f32x4 vs = zero;
      #pragma unroll
      for (int jt = 0; jt < 4; ++jt) {
        #pragma unroll
        for (int r = 0; r < 4; ++r) {
          float p = __expf(pv4[jt][r] - mx);
          pv4[jt][r] = p;
          vs[r] += p;
        }
      }
      float sm = (vs[0] + vs[1]) + (vs[2] + vs[3]);
      sm += __shfl_xor(sm, 16);
      sm += __shfl_xor(sm, 32);
      float rv = 1.0f / sm;
      // normalize, pack 4 bf16, one b64 write per (it,jt)
      #pragma unroll
      for (int jt = 0; jt < 4; ++jt) {
        unsigned int lo = (unsigned int)f2bf(pv4[jt][0] * rv) | ((unsigned int)f2bf(pv4[jt][1] * rv) << 16);
        unsigned int hi = (unsigned int)f2bf(pv4[jt][2] * rv) | ((unsigned int)f2bf(pv4[jt][3] * rv) << 16);
        u32x2 w = {lo, hi};
        *(u32x2*)(pl + i * PLD + jt * 16 + 4 * g) = w;
      }
    }

    // O = P @ V (P pre-normalized). Same-wave LDS region: no barrier needed.
    f32x4 oacc[4][2] = {};
    #pragma unroll
    for (int ktt = 0; ktt < 2; ++ktt) {
      bf16x8 pa[4];
      #pragma unroll
      for (int it = 0; it < 4; ++it)
        pa[it] = *(const bf16x8*)(pl + (it * 16 + q) * PLD + ktt * 32 + 8 * g);
      __builtin_amdgcn_s_setprio(1);
      #pragma unroll
      for (int it = 0; it < 4; ++it)
        #pragma unroll
        for (int dt = 0; dt < 2; ++dt)
          oacc[it][dt] = __builtin_amdgcn_mfma_f32_16x16x32_bf16(pa[it], bv[ktt][dt], oacc[it][dt], 0, 0, 0);
      __builtin_amdgcn_s_setprio(0);
    }

    // store fp32 output [b*49+i][h*32+d]
    #pragma unroll
    for (int it = 0; it < 4; ++it) {
      #pragma unroll
      for (int dt = 0; dt < 2; ++dt) {
        #pragma unroll
        for (int r = 0; r < 4; ++r) {
          int i = it * 16 + 4 * g + r;
          if (i < 49) {
            int d = dt * 16 + q;
            out[(size_t)(b * 49 + i) * 512 + h * 32 + d] = oacc[it][dt][r];
          }
        }
      }
    }

    if (hh < 3) {
      #pragma unroll
      for (int jt = 0; jt < 4; ++jt) ak[jt] = akn[jt];
      #pragma unroll
      for (int it = 0; it < 4; ++it) bq[it] = bqn[it];
    }
  }
}

// ---------------- launcher ----------------
extern "C" void kernel_launch(void* const* d_in, const int* in_sizes, int n_in,
                              void* d_out, int out_size, void* d_ws, size_t ws_size,
                              hipStream_t stream) {
  const float* x     = (const float*)d_in[0];
  const float* mask  = (const float*)d_in[1];
  const float* qkv_w = (const float*)d_in[2];
  const float* qkv_b = (const float*)d_in[3];
  const float* rpb   = (const float*)d_in[4];
  float* out = (float*)d_out;

  // workspace layout (bytes)
  const size_t QS_OFF   = 0;                         // 2048*16*49*32*2 = 102,760,448
  const size_t KK_OFF   = 102760448;
  const size_t VT_OFF   = 205520896;                 // 2048*16*32*56*2 = 117,440,512
  const size_t BIAS_OFF = 322961408;                 // 16*2548*2      = 81,536
  const size_t WB_OFF   = 323042944;                 // 1536*512*2     = 1,572,864
  const size_t NEED     = 324615808;                 // < old 324,687,936 (safe)
  if (ws_size < NEED) return;

  char* ws = (char*)d_ws;
  unsigned short* qsb   = (unsigned short*)(ws + QS_OFF);
  unsigned short* kkb   = (unsigned short*)(ws + KK_OFF);
  unsigned short* vtb   = (unsigned short*)(ws + VT_OFF);
  unsigned short* biasT = (unsigned short*)(ws + BIAS_OFF);
  unsigned short* wb    = (unsigned short*)(ws + WB_OFF);

  // xb (bf16 x, 103 MB) lives in d_out (205 MB fp32) — dead until win_attn
  // fully overwrites it.
  unsigned short* xb = (unsigned short*)d_out;

  conv_f2b_k<<<2048, 256, 0, stream>>>(x, xb, 6422528);        // 100352*512/8
  conv_f2b_k<<<512, 256, 0, stream>>>(qkv_w, wb, 98304);       // 1536*512/8
  build_bias_k<<<160, 256, 0, stream>>>(rpb, biasT);           // 16*2548
  qkv_gemm_k<<<9408, 256, 0, stream>>>(xb, qkv_b, wb, qsb, kkb, vtb);
  win_attn_k<<<2048, 256, 0, stream>>>(qsb, kkb, vtb, biasT, mask, out);
}